// Round 13
// baseline (174.706 us; speedup 1.0000x reference)
//
#include <hip/hip_runtime.h>
#include <math.h>

#define VN_EPS   1e-6f
#define NEG      0.2f
#define POS      0.8f   // 1 - NEG

typedef float v2f __attribute__((ext_vector_type(2)));
typedef float v4f __attribute__((ext_vector_type(4)));

// ---- DPP 16-lane (row) reductions: VALU-only, HW-verified R3-R10 -----------
template <int CTRL>
__device__ __forceinline__ float dpp_add(float v) {
    int s = __builtin_amdgcn_update_dpp(0, __float_as_int(v), CTRL, 0xf, 0xf, true);
    return v + __int_as_float(s);
}
__device__ __forceinline__ float row16_allsum(float v) {
    v = dpp_add<0x128>(v);  // row_ror:8
    v = dpp_add<0x124>(v);  // row_ror:4
    v = dpp_add<0x122>(v);  // row_ror:2
    v = dpp_add<0x121>(v);  // row_ror:1
    return v;
}
__device__ __forceinline__ float row16_sum15(float v) {
    v = dpp_add<0x118>(v);  // row_shr:8
    v = dpp_add<0x114>(v);  // row_shr:4
    v = dpp_add<0x112>(v);  // row_shr:2
    v = dpp_add<0x111>(v);  // row_shr:1
    return v;
}

// R13: TWO points per wave, lane = half*32 + p*16 + k.
//   - each 16-lane DPP row = (half, p): all 16 neighbors k of point p
//   - the fold's 32-h range splits across halves (16 h per lane) — halves the
//     dominant per-wave serial block
//   - wave count doubles to 8000 (31 waves/CU possible) — attacks the
//     residency cap that pinned R5-R10 at ~39us (occupancy 39-43%, VALUBusy
//     ~50%, time invariant to instruction count)
// gather/score-net are duplicated across halves (identical results; all
// writes disjoint). All fp32 (R9/R11/R12: bf16-MFMA fold fails the strict
// accuracy check — do not retry). All LDS traffic intra-wave, no barriers
// (HW-validated R4-R10). NOTE (R6): scores are PER-NEIGHBOR; never dedup.
__global__ __launch_bounds__(256, 8) void areconv_kernel(
    const float* __restrict__ q_pts,    // [N,3]
    const float* __restrict__ s_pts,    // [N2,3]
    const int*   __restrict__ nbr,      // [N,16]
    const float* __restrict__ wb,       // [3,256]
    const float* __restrict__ w_vn,     // [3,16]
    const float* __restrict__ wd_vn,    // [3,16]
    const float* __restrict__ w_h1,     // [16,8]
    const float* __restrict__ w_h2,     // [8,8]
    const float* __restrict__ b_h2,     // [8]
    const float* __restrict__ wd_relu,  // [32,32]
    const float* __restrict__ w_un,     // [32,64]
    const float* __restrict__ wd_un,    // [32,64]
    float* __restrict__ out,            // [N,64,3]
    int N)
{
    const float BN_SCALE = 0.999994993f;  // float32(1/sqrt(1+1e-5))

    // per-point staging, d-major [pt][d][h], stride 36 (144 B, v4f-aligned).
    __shared__ __align__(16) float featsA [8][3][36];
    __shared__ __align__(16) float feats2A[8][3][36];

    const int tid  = threadIdx.x;
    const int wv   = tid >> 6;          // 0..3
    const int lane = tid & 63;
    const int half = lane >> 5;         // h-range half (0..1)
    const int p    = (lane >> 4) & 1;   // point-in-wave (0..1)
    const int k    = lane & 15;         // neighbor index
    const int pt   = wv * 2 + p;        // point slot in block (0..7)
    const int lwp  = half * 16 + k;     // lane-within-point (0..31)
    int n = blockIdx.x * 8 + pt;
    n = (n < N) ? n : (N - 1);          // N=16000 -> never clamps

    // ---- gather + center + cross -> local frame L[c][d] (dup per half) ---
    const float qx = q_pts[n * 3 + 0];
    const float qy = q_pts[n * 3 + 1];
    const float qz = q_pts[n * 3 + 2];
    const int   id = nbr[n * 16 + k];
    const float px = s_pts[id * 3 + 0] - qx;
    const float py = s_pts[id * 3 + 1] - qy;
    const float pz = s_pts[id * 3 + 2] - qz;

    const float cx = row16_allsum(px) * 0.0625f;
    const float cy = row16_allsum(py) * 0.0625f;
    const float cz = row16_allsum(pz) * 0.0625f;

    const float rx = py * cz - pz * cy;
    const float ry = pz * cx - px * cz;
    const float rz = px * cy - py * cx;

    const float L[3][3] = {{px, py, pz}, {cx, cy, cz}, {rx, ry, rz}};

    // ---- score net VNLinearLeakyReLU(3->16)->||.|| FUSED with 16->8 conv,
    //      ROLLED over o (R10 structure; duplicated across halves) ---------
    v2f t01 = {0.f, 0.f}, t23 = t01, t45 = t01, t67 = t01;
#pragma unroll 1
    for (int o = 0; o < 16; ++o) {
        const float wv0 = w_vn[o],  wv1 = w_vn[16 + o],  wv2 = w_vn[32 + o];
        const float wd0 = wd_vn[o], wd1 = wd_vn[16 + o], wd2 = wd_vn[32 + o];
        float pv[3], dv[3];
        float dot = 0.f, dsq = 0.f;
#pragma unroll
        for (int d = 0; d < 3; ++d) {
            const float pp = BN_SCALE * (L[0][d] * wv0 + L[1][d] * wv1 + L[2][d] * wv2);
            const float dd = L[0][d] * wd0 + L[1][d] * wd1 + L[2][d] * wd2;
            pv[d] = pp; dv[d] = dd;
            dot += pp * dd;
            dsq += dd * dd;
        }
        const float f = dot * __builtin_amdgcn_rcpf(dsq + VN_EPS);
        float acc = 0.f;
#pragma unroll
        for (int d = 0; d < 3; ++d) {
            const float corr = pv[d] - f * dv[d];
            const float sel  = (dot >= 0.f) ? pv[d] : corr;
            const float a    = NEG * pv[d] + POS * sel;
            acc += a * a;
        }
        const float s = __builtin_amdgcn_sqrtf(acc);
        t01 += s * (*(const v2f*)&w_h1[o * 8 + 0]);
        t23 += s * (*(const v2f*)&w_h1[o * 8 + 2]);
        t45 += s * (*(const v2f*)&w_h1[o * 8 + 4]);
        t67 += s * (*(const v2f*)&w_h1[o * 8 + 6]);
    }
    float tt[8];
    tt[0] = fmaxf(t01[0] * BN_SCALE, 0.f);  tt[1] = fmaxf(t01[1] * BN_SCALE, 0.f);
    tt[2] = fmaxf(t23[0] * BN_SCALE, 0.f);  tt[3] = fmaxf(t23[1] * BN_SCALE, 0.f);
    tt[4] = fmaxf(t45[0] * BN_SCALE, 0.f);  tt[5] = fmaxf(t45[1] * BN_SCALE, 0.f);
    tt[6] = fmaxf(t67[0] * BN_SCALE, 0.f);  tt[7] = fmaxf(t67[1] * BN_SCALE, 0.f);

    // ---- 8->8 conv + bias, softmax over channels -------------------------
    float sc[8];
    float mx = -1e30f;
#pragma unroll
    for (int op = 0; op < 4; ++op) {
        v2f u = *(const v2f*)&b_h2[2 * op];
#pragma unroll
        for (int c = 0; c < 8; ++c)
            u += tt[c] * (*(const v2f*)&w_h2[c * 8 + 2 * op]);
        sc[2 * op + 0] = u[0];
        sc[2 * op + 1] = u[1];
        mx = fmaxf(mx, fmaxf(u[0], u[1]));
    }
    float se = 0.f;
#pragma unroll
    for (int o = 0; o < 8; ++o) { sc[o] = __expf(sc[o] - mx); se += sc[o]; }
    const float inv_se = __builtin_amdgcn_rcpf(se);
#pragma unroll
    for (int o = 0; o < 8; ++o) sc[o] *= inv_se;

    // ---- kernel-point correlation: per-lane fp32 fold over this half's
    //      16 h (4 v4f groups), project, normalize, mean over k ------------
#pragma unroll 1
    for (int grp = 0; grp < 4; ++grp) {
        const int hb = half * 16 + grp * 4;
        v4f W0 = sc[0] * (*(const v4f*)&wb[0 * 256 + hb]);
        v4f W1 = sc[0] * (*(const v4f*)&wb[1 * 256 + hb]);
        v4f W2 = sc[0] * (*(const v4f*)&wb[2 * 256 + hb]);
#pragma unroll
        for (int s = 1; s < 8; ++s) {
            const float sv = sc[s];
            W0 += sv * (*(const v4f*)&wb[0 * 256 + s * 32 + hb]);
            W1 += sv * (*(const v4f*)&wb[1 * 256 + s * 32 + hb]);
            W2 += sv * (*(const v4f*)&wb[2 * 256 + s * 32 + hb]);
        }
        v4f V0 = L[0][0] * W0 + L[1][0] * W1 + L[2][0] * W2;
        v4f V1 = L[0][1] * W0 + L[1][1] * W1 + L[2][1] * W2;
        v4f V2 = L[0][2] * W0 + L[1][2] * W1 + L[2][2] * W2;
        v4f vv = V0 * V0 + V1 * V1 + V2 * V2;
        v4f inn;
#pragma unroll
        for (int e = 0; e < 4; ++e)
            inn[e] = __builtin_amdgcn_rsqf(fmaxf(vv[e], 1e-24f)) * 0.0625f; // 1/||v|| * (1/16)
        V0 *= inn; V1 *= inn; V2 *= inn;
        v4f X0, X1, X2;
#pragma unroll
        for (int e = 0; e < 4; ++e) {
            X0[e] = row16_sum15(V0[e]);   // row = (half, p): sums this point's k
            X1[e] = row16_sum15(V1[e]);
            X2[e] = row16_sum15(V2[e]);
        }
        if (k == 15) {                    // disjoint h-ranges per half
            *(v4f*)&featsA[pt][0][hb] = X0;
            *(v4f*)&featsA[pt][1][hb] = X1;
            *(v4f*)&featsA[pt][2][hb] = X2;
        }
    }
    // intra-wave LDS write->read (in-order DS pipe + compiler lgkmcnt)

    // ---- VNLeakyReLU(32->32): 32 lanes/point, lane owns o = lwp ----------
    {
        const int o = lwp;
        float D0 = 0.f, D1 = 0.f, D2 = 0.f;
#pragma unroll 1
        for (int grp = 0; grp < 8; ++grp) {
            const int hb = grp * 4;
            const v4f f0 = *(const v4f*)&featsA[pt][0][hb];
            const v4f f1 = *(const v4f*)&featsA[pt][1][hb];
            const v4f f2 = *(const v4f*)&featsA[pt][2][hb];
#pragma unroll
            for (int e = 0; e < 4; ++e) {
                const float w = wd_relu[(hb + e) * 32 + o];
                D0 += f0[e] * w;
                D1 += f1[e] * w;
                D2 += f2[e] * w;
            }
        }
        const float p0 = featsA[pt][0][o];
        const float p1 = featsA[pt][1][o];
        const float p2 = featsA[pt][2][o];
        const float dot = p0 * D0 + p1 * D1 + p2 * D2;
        const float dsq = D0 * D0 + D1 * D1 + D2 * D2;
        const float f   = dot * __builtin_amdgcn_rcpf(dsq + VN_EPS);
        const bool  pos = (dot >= 0.f);
        feats2A[pt][0][o] = NEG * p0 + POS * (pos ? p0 : (p0 - f * D0));
        feats2A[pt][1][o] = NEG * p1 + POS * (pos ? p1 : (p1 - f * D1));
        feats2A[pt][2][o] = NEG * p2 + POS * (pos ? p2 : (p2 - f * D2));
    }

    // ---- VNLinearLeakyReLU(32->64): lane owns o = {2*lwp, 2*lwp+1} -------
    {
        v2f AU0 = {0.f, 0.f}, AU1 = AU0, AU2 = AU0;
        v2f AV0 = AU0, AV1 = AU0, AV2 = AU0;
#pragma unroll 1
        for (int grp = 0; grp < 8; ++grp) {
            const int hb = grp * 4;
            const v4f f0 = *(const v4f*)&feats2A[pt][0][hb];
            const v4f f1 = *(const v4f*)&feats2A[pt][1][hb];
            const v4f f2 = *(const v4f*)&feats2A[pt][2][hb];
#pragma unroll
            for (int e = 0; e < 4; ++e) {
                const v2f wu = *(const v2f*)&w_un [(hb + e) * 64 + 2 * lwp];
                const v2f wd = *(const v2f*)&wd_un[(hb + e) * 64 + 2 * lwp];
                AU0 += f0[e] * wu; AU1 += f1[e] * wu; AU2 += f2[e] * wu;
                AV0 += f0[e] * wd; AV1 += f1[e] * wd; AV2 += f2[e] * wd;
            }
        }
        float O[6];
#pragma unroll
        for (int j = 0; j < 2; ++j) {
            const float u0 = AU0[j] * BN_SCALE;
            const float u1 = AU1[j] * BN_SCALE;
            const float u2 = AU2[j] * BN_SCALE;
            const float v0 = AV0[j], v1 = AV1[j], v2 = AV2[j];
            const float dot = u0 * v0 + u1 * v1 + u2 * v2;
            const float dsq = v0 * v0 + v1 * v1 + v2 * v2;
            const float f   = dot * __builtin_amdgcn_rcpf(dsq + VN_EPS);
            const bool  pos = (dot >= 0.f);
            O[3 * j + 0] = NEG * u0 + POS * (pos ? u0 : (u0 - f * v0));
            O[3 * j + 1] = NEG * u1 + POS * (pos ? u1 : (u1 - f * v1));
            O[3 * j + 2] = NEG * u2 + POS * (pos ? u2 : (u2 - f * v2));
        }
        // lane owns out[n, 2*lwp .. 2*lwp+2, :] = 6 contiguous floats; the
        // point's 32 lanes cover its whole 192-float slab contiguously.
        // 24B/lane offset -> 8B-aligned: use v2f stores.
        float* dst = out + (long)n * 192 + 6 * lwp;
        *(v2f*)(dst + 0) = *(const v2f*)&O[0];
        *(v2f*)(dst + 2) = *(const v2f*)&O[2];
        *(v2f*)(dst + 4) = *(const v2f*)&O[4];
    }
}

extern "C" void kernel_launch(void* const* d_in, const int* in_sizes, int n_in,
                              void* d_out, int out_size, void* d_ws, size_t ws_size,
                              hipStream_t stream) {
    const float* q_pts   = (const float*)d_in[0];
    const float* s_pts   = (const float*)d_in[1];
    // d_in[2] = s_feats: unused by the reference
    const int*   nbr     = (const int*)  d_in[3];
    const float* wb      = (const float*)d_in[4];
    const float* w_vn    = (const float*)d_in[5];
    const float* wd_vn   = (const float*)d_in[6];
    const float* w_h1    = (const float*)d_in[7];
    const float* w_h2    = (const float*)d_in[8];
    const float* b_h2    = (const float*)d_in[9];
    const float* wd_relu = (const float*)d_in[10];
    const float* w_un    = (const float*)d_in[11];
    const float* wd_un   = (const float*)d_in[12];
    float* out = (float*)d_out;

    const int N = in_sizes[0] / 3;          // q_pts is [N,3]
    const int blocks = (N + 7) / 8;         // 8 points/block, 2 per wave
    areconv_kernel<<<blocks, 256, 0, stream>>>(
        q_pts, s_pts, nbr, wb, w_vn, wd_vn, w_h1, w_h2, b_h2,
        wd_relu, w_un, wd_un, out, N);
}

// Round 14
// 138.537 us; speedup vs baseline: 1.2611x; 1.2611x over previous
//
#include <hip/hip_runtime.h>
#include <math.h>

#define VN_EPS   1e-6f
#define NEG      0.2f
#define POS      0.8f   // 1 - NEG

typedef float v2f __attribute__((ext_vector_type(2)));
typedef float v4f __attribute__((ext_vector_type(4)));

// ---- DPP 16-lane (row) reductions: VALU-only, HW-verified R3-R13 -----------
template <int CTRL>
__device__ __forceinline__ float dpp_add(float v) {
    int s = __builtin_amdgcn_update_dpp(0, __float_as_int(v), CTRL, 0xf, 0xf, true);
    return v + __int_as_float(s);
}
__device__ __forceinline__ float row16_allsum(float v) {
    v = dpp_add<0x128>(v);  // row_ror:8
    v = dpp_add<0x124>(v);  // row_ror:4
    v = dpp_add<0x122>(v);  // row_ror:2
    v = dpp_add<0x121>(v);  // row_ror:1
    return v;
}
__device__ __forceinline__ float row16_sum15(float v) {
    v = dpp_add<0x118>(v);  // row_shr:8
    v = dpp_add<0x114>(v);  // row_shr:4
    v = dpp_add<0x112>(v);  // row_shr:2
    v = dpp_add<0x111>(v);  // row_shr:1
    return v;
}

// R14 = R13 with the VGPR squeeze removed.
// R13 post-mortem: __launch_bounds__(256,8) forced VGPR 64->32 and the
// compiler spilled ~230MB/dispatch to scratch (FETCH 2.4->147MB, WRITE
// 13->90MB) — occupancy hit 78% but time went 39->101us. The 2-pts/wave
// mapping itself is verified correct. Natural VGPR (~64) allows 32 waves/CU
// anyway (2048/64); 8000 waves give up to 31/CU.
// Mapping: lane = half*32 + p*16 + k; each DPP row = (half,p) covers point
// p's 16 neighbors; fold h-range splits across halves. All fp32 (R9/R11/R12:
// bf16-MFMA fold fails the strict accuracy check — do not retry). All LDS
// traffic intra-wave, no barriers. NOTE (R6): scores PER-NEIGHBOR, no dedup.
__global__ __launch_bounds__(256) void areconv_kernel(
    const float* __restrict__ q_pts,    // [N,3]
    const float* __restrict__ s_pts,    // [N2,3]
    const int*   __restrict__ nbr,      // [N,16]
    const float* __restrict__ wb,       // [3,256]
    const float* __restrict__ w_vn,     // [3,16]
    const float* __restrict__ wd_vn,    // [3,16]
    const float* __restrict__ w_h1,     // [16,8]
    const float* __restrict__ w_h2,     // [8,8]
    const float* __restrict__ b_h2,     // [8]
    const float* __restrict__ wd_relu,  // [32,32]
    const float* __restrict__ w_un,     // [32,64]
    const float* __restrict__ wd_un,    // [32,64]
    float* __restrict__ out,            // [N,64,3]
    int N)
{
    const float BN_SCALE = 0.999994993f;  // float32(1/sqrt(1+1e-5))

    // per-point staging, d-major [pt][d][h], stride 36 (144 B, v4f-aligned).
    __shared__ __align__(16) float featsA [8][3][36];
    __shared__ __align__(16) float feats2A[8][3][36];

    const int tid  = threadIdx.x;
    const int wv   = tid >> 6;          // 0..3
    const int lane = tid & 63;
    const int half = lane >> 5;         // h-range half (0..1)
    const int p    = (lane >> 4) & 1;   // point-in-wave (0..1)
    const int k    = lane & 15;         // neighbor index
    const int pt   = wv * 2 + p;        // point slot in block (0..7)
    const int lwp  = half * 16 + k;     // lane-within-point (0..31)
    int n = blockIdx.x * 8 + pt;
    n = (n < N) ? n : (N - 1);          // N=16000 -> never clamps

    // ---- gather + center + cross -> local frame L[c][d] (dup per half) ---
    const float qx = q_pts[n * 3 + 0];
    const float qy = q_pts[n * 3 + 1];
    const float qz = q_pts[n * 3 + 2];
    const int   id = nbr[n * 16 + k];
    const float px = s_pts[id * 3 + 0] - qx;
    const float py = s_pts[id * 3 + 1] - qy;
    const float pz = s_pts[id * 3 + 2] - qz;

    const float cx = row16_allsum(px) * 0.0625f;
    const float cy = row16_allsum(py) * 0.0625f;
    const float cz = row16_allsum(pz) * 0.0625f;

    const float rx = py * cz - pz * cy;
    const float ry = pz * cx - px * cz;
    const float rz = px * cy - py * cx;

    const float L[3][3] = {{px, py, pz}, {cx, cy, cz}, {rx, ry, rz}};

    // ---- score net VNLinearLeakyReLU(3->16)->||.|| FUSED with 16->8 conv,
    //      ROLLED over o (R10 structure; duplicated across halves) ---------
    v2f t01 = {0.f, 0.f}, t23 = t01, t45 = t01, t67 = t01;
#pragma unroll 1
    for (int o = 0; o < 16; ++o) {
        const float wv0 = w_vn[o],  wv1 = w_vn[16 + o],  wv2 = w_vn[32 + o];
        const float wd0 = wd_vn[o], wd1 = wd_vn[16 + o], wd2 = wd_vn[32 + o];
        float pv[3], dv[3];
        float dot = 0.f, dsq = 0.f;
#pragma unroll
        for (int d = 0; d < 3; ++d) {
            const float pp = BN_SCALE * (L[0][d] * wv0 + L[1][d] * wv1 + L[2][d] * wv2);
            const float dd = L[0][d] * wd0 + L[1][d] * wd1 + L[2][d] * wd2;
            pv[d] = pp; dv[d] = dd;
            dot += pp * dd;
            dsq += dd * dd;
        }
        const float f = dot * __builtin_amdgcn_rcpf(dsq + VN_EPS);
        float acc = 0.f;
#pragma unroll
        for (int d = 0; d < 3; ++d) {
            const float corr = pv[d] - f * dv[d];
            const float sel  = (dot >= 0.f) ? pv[d] : corr;
            const float a    = NEG * pv[d] + POS * sel;
            acc += a * a;
        }
        const float s = __builtin_amdgcn_sqrtf(acc);
        t01 += s * (*(const v2f*)&w_h1[o * 8 + 0]);
        t23 += s * (*(const v2f*)&w_h1[o * 8 + 2]);
        t45 += s * (*(const v2f*)&w_h1[o * 8 + 4]);
        t67 += s * (*(const v2f*)&w_h1[o * 8 + 6]);
    }
    float tt[8];
    tt[0] = fmaxf(t01[0] * BN_SCALE, 0.f);  tt[1] = fmaxf(t01[1] * BN_SCALE, 0.f);
    tt[2] = fmaxf(t23[0] * BN_SCALE, 0.f);  tt[3] = fmaxf(t23[1] * BN_SCALE, 0.f);
    tt[4] = fmaxf(t45[0] * BN_SCALE, 0.f);  tt[5] = fmaxf(t45[1] * BN_SCALE, 0.f);
    tt[6] = fmaxf(t67[0] * BN_SCALE, 0.f);  tt[7] = fmaxf(t67[1] * BN_SCALE, 0.f);

    // ---- 8->8 conv + bias, softmax over channels -------------------------
    float sc[8];
    float mx = -1e30f;
#pragma unroll
    for (int op = 0; op < 4; ++op) {
        v2f u = *(const v2f*)&b_h2[2 * op];
#pragma unroll
        for (int c = 0; c < 8; ++c)
            u += tt[c] * (*(const v2f*)&w_h2[c * 8 + 2 * op]);
        sc[2 * op + 0] = u[0];
        sc[2 * op + 1] = u[1];
        mx = fmaxf(mx, fmaxf(u[0], u[1]));
    }
    float se = 0.f;
#pragma unroll
    for (int o = 0; o < 8; ++o) { sc[o] = __expf(sc[o] - mx); se += sc[o]; }
    const float inv_se = __builtin_amdgcn_rcpf(se);
#pragma unroll
    for (int o = 0; o < 8; ++o) sc[o] *= inv_se;

    // ---- kernel-point correlation: per-lane fp32 fold over this half's
    //      16 h (4 v4f groups), project, normalize, mean over k ------------
#pragma unroll 1
    for (int grp = 0; grp < 4; ++grp) {
        const int hb = half * 16 + grp * 4;
        v4f W0 = sc[0] * (*(const v4f*)&wb[0 * 256 + hb]);
        v4f W1 = sc[0] * (*(const v4f*)&wb[1 * 256 + hb]);
        v4f W2 = sc[0] * (*(const v4f*)&wb[2 * 256 + hb]);
#pragma unroll
        for (int s = 1; s < 8; ++s) {
            const float sv = sc[s];
            W0 += sv * (*(const v4f*)&wb[0 * 256 + s * 32 + hb]);
            W1 += sv * (*(const v4f*)&wb[1 * 256 + s * 32 + hb]);
            W2 += sv * (*(const v4f*)&wb[2 * 256 + s * 32 + hb]);
        }
        v4f V0 = L[0][0] * W0 + L[1][0] * W1 + L[2][0] * W2;
        v4f V1 = L[0][1] * W0 + L[1][1] * W1 + L[2][1] * W2;
        v4f V2 = L[0][2] * W0 + L[1][2] * W1 + L[2][2] * W2;
        v4f vv = V0 * V0 + V1 * V1 + V2 * V2;
        v4f inn;
#pragma unroll
        for (int e = 0; e < 4; ++e)
            inn[e] = __builtin_amdgcn_rsqf(fmaxf(vv[e], 1e-24f)) * 0.0625f; // 1/||v|| * (1/16)
        V0 *= inn; V1 *= inn; V2 *= inn;
        v4f X0, X1, X2;
#pragma unroll
        for (int e = 0; e < 4; ++e) {
            X0[e] = row16_sum15(V0[e]);   // row = (half, p): sums this point's k
            X1[e] = row16_sum15(V1[e]);
            X2[e] = row16_sum15(V2[e]);
        }
        if (k == 15) {                    // disjoint h-ranges per half
            *(v4f*)&featsA[pt][0][hb] = X0;
            *(v4f*)&featsA[pt][1][hb] = X1;
            *(v4f*)&featsA[pt][2][hb] = X2;
        }
    }
    // intra-wave LDS write->read (in-order DS pipe + compiler lgkmcnt)

    // ---- VNLeakyReLU(32->32): 32 lanes/point, lane owns o = lwp ----------
    {
        const int o = lwp;
        float D0 = 0.f, D1 = 0.f, D2 = 0.f;
#pragma unroll 1
        for (int grp = 0; grp < 8; ++grp) {
            const int hb = grp * 4;
            const v4f f0 = *(const v4f*)&featsA[pt][0][hb];
            const v4f f1 = *(const v4f*)&featsA[pt][1][hb];
            const v4f f2 = *(const v4f*)&featsA[pt][2][hb];
#pragma unroll
            for (int e = 0; e < 4; ++e) {
                const float w = wd_relu[(hb + e) * 32 + o];
                D0 += f0[e] * w;
                D1 += f1[e] * w;
                D2 += f2[e] * w;
            }
        }
        const float p0 = featsA[pt][0][o];
        const float p1 = featsA[pt][1][o];
        const float p2 = featsA[pt][2][o];
        const float dot = p0 * D0 + p1 * D1 + p2 * D2;
        const float dsq = D0 * D0 + D1 * D1 + D2 * D2;
        const float f   = dot * __builtin_amdgcn_rcpf(dsq + VN_EPS);
        const bool  pos = (dot >= 0.f);
        feats2A[pt][0][o] = NEG * p0 + POS * (pos ? p0 : (p0 - f * D0));
        feats2A[pt][1][o] = NEG * p1 + POS * (pos ? p1 : (p1 - f * D1));
        feats2A[pt][2][o] = NEG * p2 + POS * (pos ? p2 : (p2 - f * D2));
    }

    // ---- VNLinearLeakyReLU(32->64): lane owns o = {2*lwp, 2*lwp+1} -------
    {
        v2f AU0 = {0.f, 0.f}, AU1 = AU0, AU2 = AU0;
        v2f AV0 = AU0, AV1 = AU0, AV2 = AU0;
#pragma unroll 1
        for (int grp = 0; grp < 8; ++grp) {
            const int hb = grp * 4;
            const v4f f0 = *(const v4f*)&feats2A[pt][0][hb];
            const v4f f1 = *(const v4f*)&feats2A[pt][1][hb];
            const v4f f2 = *(const v4f*)&feats2A[pt][2][hb];
#pragma unroll
            for (int e = 0; e < 4; ++e) {
                const v2f wu = *(const v2f*)&w_un [(hb + e) * 64 + 2 * lwp];
                const v2f wd = *(const v2f*)&wd_un[(hb + e) * 64 + 2 * lwp];
                AU0 += f0[e] * wu; AU1 += f1[e] * wu; AU2 += f2[e] * wu;
                AV0 += f0[e] * wd; AV1 += f1[e] * wd; AV2 += f2[e] * wd;
            }
        }
        float O[6];
#pragma unroll
        for (int j = 0; j < 2; ++j) {
            const float u0 = AU0[j] * BN_SCALE;
            const float u1 = AU1[j] * BN_SCALE;
            const float u2 = AU2[j] * BN_SCALE;
            const float v0 = AV0[j], v1 = AV1[j], v2 = AV2[j];
            const float dot = u0 * v0 + u1 * v1 + u2 * v2;
            const float dsq = v0 * v0 + v1 * v1 + v2 * v2;
            const float f   = dot * __builtin_amdgcn_rcpf(dsq + VN_EPS);
            const bool  pos = (dot >= 0.f);
            O[3 * j + 0] = NEG * u0 + POS * (pos ? u0 : (u0 - f * v0));
            O[3 * j + 1] = NEG * u1 + POS * (pos ? u1 : (u1 - f * v1));
            O[3 * j + 2] = NEG * u2 + POS * (pos ? u2 : (u2 - f * v2));
        }
        // lane owns out[n, 2*lwp .. 2*lwp+2, :] = 6 contiguous floats; the
        // point's 32 lanes cover its whole 192-float slab contiguously.
        float* dst = out + (long)n * 192 + 6 * lwp;
        *(v2f*)(dst + 0) = *(const v2f*)&O[0];
        *(v2f*)(dst + 2) = *(const v2f*)&O[2];
        *(v2f*)(dst + 4) = *(const v2f*)&O[4];
    }
}

extern "C" void kernel_launch(void* const* d_in, const int* in_sizes, int n_in,
                              void* d_out, int out_size, void* d_ws, size_t ws_size,
                              hipStream_t stream) {
    const float* q_pts   = (const float*)d_in[0];
    const float* s_pts   = (const float*)d_in[1];
    // d_in[2] = s_feats: unused by the reference
    const int*   nbr     = (const int*)  d_in[3];
    const float* wb      = (const float*)d_in[4];
    const float* w_vn    = (const float*)d_in[5];
    const float* wd_vn   = (const float*)d_in[6];
    const float* w_h1    = (const float*)d_in[7];
    const float* w_h2    = (const float*)d_in[8];
    const float* b_h2    = (const float*)d_in[9];
    const float* wd_relu = (const float*)d_in[10];
    const float* w_un    = (const float*)d_in[11];
    const float* wd_un   = (const float*)d_in[12];
    float* out = (float*)d_out;

    const int N = in_sizes[0] / 3;          // q_pts is [N,3]
    const int blocks = (N + 7) / 8;         // 8 points/block, 2 per wave
    areconv_kernel<<<blocks, 256, 0, stream>>>(
        q_pts, s_pts, nbr, wb, w_vn, wd_vn, w_h1, w_h2, b_h2,
        wd_relu, w_un, wd_un, out, N);
}

// Round 15
// 113.414 us; speedup vs baseline: 1.5404x; 1.2215x over previous
//
#include <hip/hip_runtime.h>
#include <math.h>

#define VN_EPS   1e-6f
#define NEG      0.2f
#define POS      0.8f   // 1 - NEG

typedef float v2f __attribute__((ext_vector_type(2)));
typedef float v4f __attribute__((ext_vector_type(4)));

// ---- packed fp32 (VOP3P dual-issue): the compiler does NOT auto-generate
// v_pk_*_f32 from vector-typed C (R4/R10 calibration: v4f lowers to scalar
// v_fma) — force it via asm. IEEE-identical per element to v_fma_f32. ------
__device__ __forceinline__ v2f pk_fma(v2f a, v2f b, v2f c) {
    v2f d;
    asm("v_pk_fma_f32 %0, %1, %2, %3" : "=v"(d) : "v"(a), "v"(b), "v"(c));
    return d;
}
__device__ __forceinline__ v2f pk_mul(v2f a, v2f b) {
    v2f d;
    asm("v_pk_mul_f32 %0, %1, %2" : "=v"(d) : "v"(a), "v"(b));
    return d;
}

// ---- DPP 16-lane (row) reductions: VALU-only, HW-verified R3-R14 -----------
template <int CTRL>
__device__ __forceinline__ float dpp_add(float v) {
    int s = __builtin_amdgcn_update_dpp(0, __float_as_int(v), CTRL, 0xf, 0xf, true);
    return v + __int_as_float(s);
}
__device__ __forceinline__ float row16_allsum(float v) {
    v = dpp_add<0x128>(v);  // row_ror:8
    v = dpp_add<0x124>(v);  // row_ror:4
    v = dpp_add<0x122>(v);  // row_ror:2
    v = dpp_add<0x121>(v);  // row_ror:1
    return v;
}
__device__ __forceinline__ float row16_sum15(float v) {
    v = dpp_add<0x118>(v);  // row_shr:8
    v = dpp_add<0x114>(v);  // row_shr:4
    v = dpp_add<0x112>(v);  // row_shr:2
    v = dpp_add<0x111>(v);  // row_shr:1
    return v;
}

// R15 = R10 config (4 pts/wave, lane=p*16+k, 128 thd, 8 pts/block — best
// measured ~39us) + v_pk_fma_f32 packing of the two dominant FMA blocks.
// Cross-round model (R1-R14): time ≈ 2 × VALU-busy-time at ~50% issue
// efficiency; the only working lever is real instruction count.
// R13: never force min-waves (spills). R14: never duplicate the score-net.
// R9/R11/R12: bf16-MFMA fold fails the strict accuracy check — do not retry.
// R6: scores are PER-NEIGHBOR — never dedup the fold across k.
__global__ __launch_bounds__(128) void areconv_kernel(
    const float* __restrict__ q_pts,    // [N,3]
    const float* __restrict__ s_pts,    // [N2,3]
    const int*   __restrict__ nbr,      // [N,16]
    const float* __restrict__ wb,       // [3,256]
    const float* __restrict__ w_vn,     // [3,16]
    const float* __restrict__ wd_vn,    // [3,16]
    const float* __restrict__ w_h1,     // [16,8]
    const float* __restrict__ w_h2,     // [8,8]
    const float* __restrict__ b_h2,     // [8]
    const float* __restrict__ wd_relu,  // [32,32]
    const float* __restrict__ w_un,     // [32,64]
    const float* __restrict__ wd_un,    // [32,64]
    float* __restrict__ out,            // [N,64,3]
    int N)
{
    const float BN_SCALE = 0.999994993f;  // float32(1/sqrt(1+1e-5))

    __shared__ __align__(16) float featsA [8][3][36];
    __shared__ __align__(16) float feats2A[8][3][36];

    const int tid  = threadIdx.x;
    const int wv   = tid >> 6;        // 0..1
    const int lane = tid & 63;
    const int p    = lane >> 4;       // DPP row = point-in-wave
    const int k    = lane & 15;       // neighbor index
    const int bp   = wv * 4 + p;      // point slot in block (0..7)
    int n = blockIdx.x * 8 + bp;
    n = (n < N) ? n : (N - 1);        // N=16000 -> never clamps

    // ---- gather + center + cross -> local frame L[c][d] ------------------
    const float qx = q_pts[n * 3 + 0];
    const float qy = q_pts[n * 3 + 1];
    const float qz = q_pts[n * 3 + 2];
    const int   id = nbr[n * 16 + k];
    const float px = s_pts[id * 3 + 0] - qx;
    const float py = s_pts[id * 3 + 1] - qy;
    const float pz = s_pts[id * 3 + 2] - qz;

    const float cx = row16_allsum(px) * 0.0625f;
    const float cy = row16_allsum(py) * 0.0625f;
    const float cz = row16_allsum(pz) * 0.0625f;

    const float rx = py * cz - pz * cy;
    const float ry = pz * cx - px * cz;
    const float rz = px * cy - py * cx;

    const float L[3][3] = {{px, py, pz}, {cx, cy, cz}, {rx, ry, rz}};

    // ---- score net VNLinearLeakyReLU(3->16)->||.|| FUSED with 16->8 conv,
    //      ROLLED over o (R10) --------------------------------------------
    v2f t01 = {0.f, 0.f}, t23 = t01, t45 = t01, t67 = t01;
#pragma unroll 1
    for (int o = 0; o < 16; ++o) {
        const float wv0 = w_vn[o],  wv1 = w_vn[16 + o],  wv2 = w_vn[32 + o];
        const float wd0 = wd_vn[o], wd1 = wd_vn[16 + o], wd2 = wd_vn[32 + o];
        float pv[3], dv[3];
        float dot = 0.f, dsq = 0.f;
#pragma unroll
        for (int d = 0; d < 3; ++d) {
            const float pp = BN_SCALE * (L[0][d] * wv0 + L[1][d] * wv1 + L[2][d] * wv2);
            const float dd = L[0][d] * wd0 + L[1][d] * wd1 + L[2][d] * wd2;
            pv[d] = pp; dv[d] = dd;
            dot += pp * dd;
            dsq += dd * dd;
        }
        const float f = dot * __builtin_amdgcn_rcpf(dsq + VN_EPS);
        float acc = 0.f;
#pragma unroll
        for (int d = 0; d < 3; ++d) {
            const float corr = pv[d] - f * dv[d];
            const float sel  = (dot >= 0.f) ? pv[d] : corr;
            const float a    = NEG * pv[d] + POS * sel;
            acc += a * a;
        }
        const float s = __builtin_amdgcn_sqrtf(acc);
        t01 += s * (*(const v2f*)&w_h1[o * 8 + 0]);
        t23 += s * (*(const v2f*)&w_h1[o * 8 + 2]);
        t45 += s * (*(const v2f*)&w_h1[o * 8 + 4]);
        t67 += s * (*(const v2f*)&w_h1[o * 8 + 6]);
    }
    float tt[8];
    tt[0] = fmaxf(t01[0] * BN_SCALE, 0.f);  tt[1] = fmaxf(t01[1] * BN_SCALE, 0.f);
    tt[2] = fmaxf(t23[0] * BN_SCALE, 0.f);  tt[3] = fmaxf(t23[1] * BN_SCALE, 0.f);
    tt[4] = fmaxf(t45[0] * BN_SCALE, 0.f);  tt[5] = fmaxf(t45[1] * BN_SCALE, 0.f);
    tt[6] = fmaxf(t67[0] * BN_SCALE, 0.f);  tt[7] = fmaxf(t67[1] * BN_SCALE, 0.f);

    // ---- 8->8 conv + bias, softmax over channels -------------------------
    float sc[8];
    float mx = -1e30f;
#pragma unroll
    for (int op = 0; op < 4; ++op) {
        v2f u = *(const v2f*)&b_h2[2 * op];
#pragma unroll
        for (int c = 0; c < 8; ++c)
            u += tt[c] * (*(const v2f*)&w_h2[c * 8 + 2 * op]);
        sc[2 * op + 0] = u[0];
        sc[2 * op + 1] = u[1];
        mx = fmaxf(mx, fmaxf(u[0], u[1]));
    }
    float se = 0.f;
#pragma unroll
    for (int o = 0; o < 8; ++o) { sc[o] = __expf(sc[o] - mx); se += sc[o]; }
    const float inv_se = __builtin_amdgcn_rcpf(se);
#pragma unroll
    for (int o = 0; o < 8; ++o) sc[o] *= inv_se;

    // duplicated-scalar pairs for VOP3P operands (built once)
    v2f sc2[8];
#pragma unroll
    for (int s = 0; s < 8; ++s) sc2[s] = (v2f){sc[s], sc[s]};
    v2f L2[3][3];
#pragma unroll
    for (int c = 0; c < 3; ++c)
#pragma unroll
        for (int d = 0; d < 3; ++d) L2[c][d] = (v2f){L[c][d], L[c][d]};

    // ---- kernel-point correlation: per-lane fp32 fold (pk-packed),
    //      project, normalize, mean over k. ROLLED over h-groups -----------
#pragma unroll 1
    for (int grp = 0; grp < 8; ++grp) {
        const int hb = grp * 4;
        const float* wb0 = &wb[0 * 256 + hb];
        const float* wb1 = &wb[1 * 256 + hb];
        const float* wb2 = &wb[2 * 256 + hb];
        v2f W0a = pk_mul(sc2[0], *(const v2f*)&wb0[0]);
        v2f W0b = pk_mul(sc2[0], *(const v2f*)&wb0[2]);
        v2f W1a = pk_mul(sc2[0], *(const v2f*)&wb1[0]);
        v2f W1b = pk_mul(sc2[0], *(const v2f*)&wb1[2]);
        v2f W2a = pk_mul(sc2[0], *(const v2f*)&wb2[0]);
        v2f W2b = pk_mul(sc2[0], *(const v2f*)&wb2[2]);
#pragma unroll
        for (int s = 1; s < 8; ++s) {
            W0a = pk_fma(sc2[s], *(const v2f*)&wb0[s * 32 + 0], W0a);
            W0b = pk_fma(sc2[s], *(const v2f*)&wb0[s * 32 + 2], W0b);
            W1a = pk_fma(sc2[s], *(const v2f*)&wb1[s * 32 + 0], W1a);
            W1b = pk_fma(sc2[s], *(const v2f*)&wb1[s * 32 + 2], W1b);
            W2a = pk_fma(sc2[s], *(const v2f*)&wb2[s * 32 + 0], W2a);
            W2b = pk_fma(sc2[s], *(const v2f*)&wb2[s * 32 + 2], W2b);
        }
        // projection V_d = sum_c L[c][d] * W_c  (pk-packed)
        v2f V0a = pk_fma(L2[2][0], W2a, pk_fma(L2[1][0], W1a, pk_mul(L2[0][0], W0a)));
        v2f V0b = pk_fma(L2[2][0], W2b, pk_fma(L2[1][0], W1b, pk_mul(L2[0][0], W0b)));
        v2f V1a = pk_fma(L2[2][1], W2a, pk_fma(L2[1][1], W1a, pk_mul(L2[0][1], W0a)));
        v2f V1b = pk_fma(L2[2][1], W2b, pk_fma(L2[1][1], W1b, pk_mul(L2[0][1], W0b)));
        v2f V2a = pk_fma(L2[2][2], W2a, pk_fma(L2[1][2], W1a, pk_mul(L2[0][2], W0a)));
        v2f V2b = pk_fma(L2[2][2], W2b, pk_fma(L2[1][2], W1b, pk_mul(L2[0][2], W0b)));
        // squared norms (pk-packed)
        v2f vva = pk_fma(V2a, V2a, pk_fma(V1a, V1a, pk_mul(V0a, V0a)));
        v2f vvb = pk_fma(V2b, V2b, pk_fma(V1b, V1b, pk_mul(V0b, V0b)));
        // per-element: normalize (fold 1/16), DPP mean over k -> lane 15
        const float v0e[4] = {V0a[0], V0a[1], V0b[0], V0b[1]};
        const float v1e[4] = {V1a[0], V1a[1], V1b[0], V1b[1]};
        const float v2e[4] = {V2a[0], V2a[1], V2b[0], V2b[1]};
        const float vve[4] = {vva[0], vva[1], vvb[0], vvb[1]};
        v4f X0, X1, X2;
#pragma unroll
        for (int e = 0; e < 4; ++e) {
            const float inn = __builtin_amdgcn_rsqf(fmaxf(vve[e], 1e-24f)) * 0.0625f;
            X0[e] = row16_sum15(v0e[e] * inn);
            X1[e] = row16_sum15(v1e[e] * inn);
            X2[e] = row16_sum15(v2e[e] * inn);
        }
        if (k == 15) {
            *(v4f*)&featsA[bp][0][hb] = X0;
            *(v4f*)&featsA[bp][1][hb] = X1;
            *(v4f*)&featsA[bp][2][hb] = X2;
        }
    }
    // intra-wave LDS write->read (in-order DS pipe + compiler lgkmcnt)

    // ---- VNLeakyReLU(32->32): lane owns o = {2k, 2k+1}; ROLLED over h ----
    {
        v2f D0 = {0.f, 0.f}, D1 = D0, D2 = D0;
#pragma unroll 1
        for (int grp = 0; grp < 8; ++grp) {
            const int hb = grp * 4;
            const v4f f0 = *(const v4f*)&featsA[bp][0][hb];
            const v4f f1 = *(const v4f*)&featsA[bp][1][hb];
            const v4f f2 = *(const v4f*)&featsA[bp][2][hb];
#pragma unroll
            for (int e = 0; e < 4; ++e) {
                const v2f w = *(const v2f*)&wd_relu[(hb + e) * 32 + 2 * k];
                const v2f f0d = {f0[e], f0[e]};
                const v2f f1d = {f1[e], f1[e]};
                const v2f f2d = {f2[e], f2[e]};
                D0 = pk_fma(f0d, w, D0);
                D1 = pk_fma(f1d, w, D1);
                D2 = pk_fma(f2d, w, D2);
            }
        }
        v2f R0, R1, R2;
#pragma unroll
        for (int j = 0; j < 2; ++j) {
            const int o = 2 * k + j;
            const float p0 = featsA[bp][0][o];
            const float p1 = featsA[bp][1][o];
            const float p2 = featsA[bp][2][o];
            const float d0 = D0[j], d1 = D1[j], d2 = D2[j];
            const float dot = p0 * d0 + p1 * d1 + p2 * d2;
            const float dsq = d0 * d0 + d1 * d1 + d2 * d2;
            const float f   = dot * __builtin_amdgcn_rcpf(dsq + VN_EPS);
            const bool  pos = (dot >= 0.f);
            R0[j] = NEG * p0 + POS * (pos ? p0 : (p0 - f * d0));
            R1[j] = NEG * p1 + POS * (pos ? p1 : (p1 - f * d1));
            R2[j] = NEG * p2 + POS * (pos ? p2 : (p2 - f * d2));
        }
        *(v2f*)&feats2A[bp][0][2 * k] = R0;
        *(v2f*)&feats2A[bp][1][2 * k] = R1;
        *(v2f*)&feats2A[bp][2][2 * k] = R2;
    }

    // ---- VNLinearLeakyReLU(32->64): lane owns o = 4k..4k+3; pk-packed ----
    {
        v2f AU0a = {0.f, 0.f}, AU0b = AU0a, AU1a = AU0a, AU1b = AU0a;
        v2f AU2a = AU0a, AU2b = AU0a;
        v2f AV0a = AU0a, AV0b = AU0a, AV1a = AU0a, AV1b = AU0a;
        v2f AV2a = AU0a, AV2b = AU0a;
#pragma unroll 1
        for (int grp = 0; grp < 8; ++grp) {
            const int hb = grp * 4;
            const v4f f0 = *(const v4f*)&feats2A[bp][0][hb];
            const v4f f1 = *(const v4f*)&feats2A[bp][1][hb];
            const v4f f2 = *(const v4f*)&feats2A[bp][2][hb];
#pragma unroll
            for (int e = 0; e < 4; ++e) {
                const v2f wua = *(const v2f*)&w_un [(hb + e) * 64 + 4 * k + 0];
                const v2f wub = *(const v2f*)&w_un [(hb + e) * 64 + 4 * k + 2];
                const v2f wda = *(const v2f*)&wd_un[(hb + e) * 64 + 4 * k + 0];
                const v2f wdb = *(const v2f*)&wd_un[(hb + e) * 64 + 4 * k + 2];
                const v2f f0d = {f0[e], f0[e]};
                const v2f f1d = {f1[e], f1[e]};
                const v2f f2d = {f2[e], f2[e]};
                AU0a = pk_fma(f0d, wua, AU0a);  AU0b = pk_fma(f0d, wub, AU0b);
                AU1a = pk_fma(f1d, wua, AU1a);  AU1b = pk_fma(f1d, wub, AU1b);
                AU2a = pk_fma(f2d, wua, AU2a);  AU2b = pk_fma(f2d, wub, AU2b);
                AV0a = pk_fma(f0d, wda, AV0a);  AV0b = pk_fma(f0d, wdb, AV0b);
                AV1a = pk_fma(f1d, wda, AV1a);  AV1b = pk_fma(f1d, wdb, AV1b);
                AV2a = pk_fma(f2d, wda, AV2a);  AV2b = pk_fma(f2d, wdb, AV2b);
            }
        }
        const float AU0e[4] = {AU0a[0], AU0a[1], AU0b[0], AU0b[1]};
        const float AU1e[4] = {AU1a[0], AU1a[1], AU1b[0], AU1b[1]};
        const float AU2e[4] = {AU2a[0], AU2a[1], AU2b[0], AU2b[1]};
        const float AV0e[4] = {AV0a[0], AV0a[1], AV0b[0], AV0b[1]};
        const float AV1e[4] = {AV1a[0], AV1a[1], AV1b[0], AV1b[1]};
        const float AV2e[4] = {AV2a[0], AV2a[1], AV2b[0], AV2b[1]};
        float O[12];
#pragma unroll
        for (int e = 0; e < 4; ++e) {
            const float u0 = AU0e[e] * BN_SCALE;
            const float u1 = AU1e[e] * BN_SCALE;
            const float u2 = AU2e[e] * BN_SCALE;
            const float v0 = AV0e[e], v1 = AV1e[e], v2 = AV2e[e];
            const float dot = u0 * v0 + u1 * v1 + u2 * v2;
            const float dsq = v0 * v0 + v1 * v1 + v2 * v2;
            const float f   = dot * __builtin_amdgcn_rcpf(dsq + VN_EPS);
            const bool  pos = (dot >= 0.f);
            O[3 * e + 0] = NEG * u0 + POS * (pos ? u0 : (u0 - f * v0));
            O[3 * e + 1] = NEG * u1 + POS * (pos ? u1 : (u1 - f * v1));
            O[3 * e + 2] = NEG * u2 + POS * (pos ? u2 : (u2 - f * v2));
        }
        // lane k covers out[n, 4k..4k+4, :] = 12 contiguous floats; 16 lanes
        // cover the point's whole 192-float slab contiguously.
        float* dst = out + (long)n * 192 + 12 * k;
        *(v4f*)(dst + 0) = *(const v4f*)&O[0];
        *(v4f*)(dst + 4) = *(const v4f*)&O[4];
        *(v4f*)(dst + 8) = *(const v4f*)&O[8];
    }
}

extern "C" void kernel_launch(void* const* d_in, const int* in_sizes, int n_in,
                              void* d_out, int out_size, void* d_ws, size_t ws_size,
                              hipStream_t stream) {
    const float* q_pts   = (const float*)d_in[0];
    const float* s_pts   = (const float*)d_in[1];
    // d_in[2] = s_feats: unused by the reference
    const int*   nbr     = (const int*)  d_in[3];
    const float* wb      = (const float*)d_in[4];
    const float* w_vn    = (const float*)d_in[5];
    const float* wd_vn   = (const float*)d_in[6];
    const float* w_h1    = (const float*)d_in[7];
    const float* w_h2    = (const float*)d_in[8];
    const float* b_h2    = (const float*)d_in[9];
    const float* wd_relu = (const float*)d_in[10];
    const float* w_un    = (const float*)d_in[11];
    const float* wd_un   = (const float*)d_in[12];
    float* out = (float*)d_out;

    const int N = in_sizes[0] / 3;          // q_pts is [N,3]
    const int blocks = (N + 7) / 8;         // 8 points/block, 4 per wave
    areconv_kernel<<<blocks, 128, 0, stream>>>(
        q_pts, s_pts, nbr, wb, w_vn, wd_vn, w_h1, w_h2, b_h2,
        wd_relu, w_un, wd_un, out, N);
}